// Round 6
// baseline (146.847 us; speedup 1.0000x reference)
//
#include <hip/hip_runtime.h>

// out[1024][1024] = relu(a @ feats^T) @ relu(b @ feats^T)^T
//   a,b: [1024][2048] fp32, feats: [128][2048] fp32, out fp32.
// Pipeline (2 dispatches):
//   gemm1_red: grid (64,8) = 32-row M-stripes x 8 K-splits (K=256, 8 iters of
//              32) -> fp32 partials; per-stripe completion counter; the LAST
//              split-block for a stripe (no spin) pulls the other 7 partials
//              (L2-hot), adds to its register acc, relu+cvt, writes bf16 fk.
//   gemm2    : 64x64 out tiles via MFMA on relu'd bf16 fk (R4-verbatim).
// Lessons: grid.sync (R1), per-element atomics (R2), reduce-fused-into-gemm2
// (R5: 131 MB L3 reads) all cost more than they save; ~44 us ws poison-fill
// is a fixed floor term. Counters live in __device__ bss (NOT poisoned ws),
// self-cleaning so graph replays start at 0.

typedef __attribute__((ext_vector_type(8))) __bf16 bf16x8;
typedef __attribute__((ext_vector_type(4))) __bf16 bf16x4;
typedef __attribute__((ext_vector_type(4))) float floatx4;

#define KD     2048   // inner K of gemm1
#define NF     128    // feature count = K of gemm2
#define NA     1024   // rows of a (= rows of b = out dim)
#define NPART  8      // K-splits (K=256 each)
#define KSL    256    // K per split
#define FKN    (2048 * 128)

__device__ int g_ctr[64];   // per-stripe completion counters, zero-init, self-cleaning

static __device__ inline bf16x8 cvt8(float4 u, float4 v) {
    bf16x8 s;
    s[0] = (__bf16)u.x; s[1] = (__bf16)u.y; s[2] = (__bf16)u.z; s[3] = (__bf16)u.w;
    s[4] = (__bf16)v.x; s[5] = (__bf16)v.y; s[6] = (__bf16)v.z; s[7] = (__bf16)v.w;
    return s;
}

static __device__ inline bf16x4 cvt4(float4 u) {
    bf16x4 s;
    s[0] = (__bf16)u.x; s[1] = (__bf16)u.y; s[2] = (__bf16)u.z; s[3] = (__bf16)u.w;
    return s;
}

// ---- gemm1_red: partials + last-arriver tail reduce ----
// block = 4 waves; wave w covers feat-cols [w*32, w*32+32). 8 K-iters of 32.
__global__ __launch_bounds__(256) void gemm1_red(const float* __restrict__ A,
                                                 const float* __restrict__ B,
                                                 const float* __restrict__ F,
                                                 float* __restrict__ part,
                                                 __bf16* __restrict__ fkb) {
    __shared__ __bf16 Xs[32 * 40];    // 32 rows x 32 K-cols, stride 40
    __shared__ __bf16 Fs[128 * 40];   // 128 feat-rows x 32 K-cols
    __shared__ int s_old;

    const int t    = threadIdx.x;
    const int m0   = blockIdx.x * 32;
    const int s    = blockIdx.y;
    const int k0   = s * KSL;
    const float* src = (m0 < NA) ? (A + (size_t)m0 * KD)
                                 : (B + (size_t)(m0 - NA) * KD);

    const int lane = t & 63;
    const int w    = t >> 6;
    const int ln   = lane & 15;
    const int quad = lane >> 4;
    const int q8   = quad * 8;

    floatx4 acc[2][2];
#pragma unroll
    for (int mt = 0; mt < 2; mt++)
#pragma unroll
        for (int nt = 0; nt < 2; nt++)
            acc[mt][nt] = (floatx4){0.f, 0.f, 0.f, 0.f};

    const int xrow = t >> 3, xcol = (t & 7) * 4;    // 32 rows x 32 cols, 4 floats/thr
    const int frow = t >> 1, fcol = (t & 1) * 16;   // 128 rows x 32 cols, 16 floats/thr
    const float* xp = src + (size_t)xrow * KD + (k0 + xcol);
    const float* fp = F   + (size_t)frow * KD + (k0 + fcol);

    // register prefetch of kk=0
    float4 xu = *(const float4*)(xp + 0);
    float4 f0 = *(const float4*)(fp + 0);
    float4 f1 = *(const float4*)(fp + 4);
    float4 f2 = *(const float4*)(fp + 8);
    float4 f3 = *(const float4*)(fp + 12);

#pragma unroll
    for (int kk = 0; kk < KSL; kk += 32) {
        *(bf16x4*)&Xs[xrow * 40 + xcol]     = cvt4(xu);
        *(bf16x8*)&Fs[frow * 40 + fcol]     = cvt8(f0, f1);
        *(bf16x8*)&Fs[frow * 40 + fcol + 8] = cvt8(f2, f3);
        __syncthreads();

        if (kk + 32 < KSL) {   // prefetch next K-chunk while MFMAs run
            xu = *(const float4*)(xp + kk + 32);
            f0 = *(const float4*)(fp + kk + 32);
            f1 = *(const float4*)(fp + kk + 36);
            f2 = *(const float4*)(fp + kk + 40);
            f3 = *(const float4*)(fp + kk + 44);
        }

        bf16x8 bfrag[2];
#pragma unroll
        for (int nt = 0; nt < 2; nt++)
            bfrag[nt] = *(const bf16x8*)&Fs[(w * 32 + nt * 16 + ln) * 40 + q8];
#pragma unroll
        for (int mt = 0; mt < 2; mt++) {
            bf16x8 af = *(const bf16x8*)&Xs[(mt * 16 + ln) * 40 + q8];
#pragma unroll
            for (int nt = 0; nt < 2; nt++)
                acc[mt][nt] = __builtin_amdgcn_mfma_f32_16x16x32_bf16(
                    af, bfrag[nt], acc[mt][nt], 0, 0, 0);
        }
        __syncthreads();
    }

    // store this split's partial
    float* pdst = part + (size_t)s * FKN;
#pragma unroll
    for (int mt = 0; mt < 2; mt++)
#pragma unroll
        for (int nt = 0; nt < 2; nt++)
#pragma unroll
            for (int r = 0; r < 4; r++) {
                int row = m0 + mt * 16 + quad * 4 + r;
                int col = w * 32 + nt * 16 + ln;
                pdst[(size_t)row * NF + col] = acc[mt][nt][r];
            }

    // completion count: release our stores, bump the stripe counter
    __threadfence();
    if (t == 0)
        s_old = __hip_atomic_fetch_add(&g_ctr[blockIdx.x], 1,
                                       __ATOMIC_ACQ_REL, __HIP_MEMORY_SCOPE_AGENT);
    __syncthreads();

    if (s_old == NPART - 1) {   // last arriver: others' partials are visible
        __threadfence();
#pragma unroll
        for (int s2 = 0; s2 < NPART; s2++) {
            if (s2 == s) continue;
            const float* ps = part + (size_t)s2 * FKN;
#pragma unroll
            for (int mt = 0; mt < 2; mt++)
#pragma unroll
                for (int nt = 0; nt < 2; nt++)
#pragma unroll
                    for (int r = 0; r < 4; r++) {
                        int row = m0 + mt * 16 + quad * 4 + r;
                        int col = w * 32 + nt * 16 + ln;
                        acc[mt][nt][r] += ps[(size_t)row * NF + col];
                    }
        }
#pragma unroll
        for (int mt = 0; mt < 2; mt++)
#pragma unroll
            for (int nt = 0; nt < 2; nt++)
#pragma unroll
                for (int r = 0; r < 4; r++) {
                    int row = m0 + mt * 16 + quad * 4 + r;
                    int col = w * 32 + nt * 16 + ln;
                    fkb[(size_t)row * NF + col] = (__bf16)fmaxf(acc[mt][nt][r], 0.f);
                }
        if (t == 0) atomicExch(&g_ctr[blockIdx.x], 0);   // self-clean for next replay
    }
}

// ---- gemm2: out[i][j] = sum_f fkb[i][f] * fkb[1024+j][f] (already relu'd) ----
// grid (16,16): 64x64 out tiles; block = 4 waves in 2x2. (R4-verbatim)
__global__ __launch_bounds__(256) void gemm2(const __bf16* __restrict__ fkb,
                                             float* __restrict__ out) {
    __shared__ __bf16 Ps[64 * 136];
    __shared__ __bf16 Qs[64 * 136];

    const int t    = threadIdx.x;
    const int i0   = blockIdx.y * 64;
    const int j0   = blockIdx.x * 64;
    const int lane = t & 63;
    const int w    = t >> 6;
    const int wm   = w & 1;
    const int wn   = w >> 1;
    const int ln   = lane & 15;
    const int quad = lane >> 4;
    const int q8   = quad * 8;

    const int prow = t >> 2, pcol = (t & 3) * 32;
    {
        const __bf16* p = fkb + (size_t)(i0 + prow) * NF + pcol;
        const __bf16* q = fkb + (size_t)(NA + j0 + prow) * NF + pcol;
#pragma unroll
        for (int c = 0; c < 32; c += 8) {
            *(bf16x8*)&Ps[prow * 136 + pcol + c] = *(const bf16x8*)(p + c);
            *(bf16x8*)&Qs[prow * 136 + pcol + c] = *(const bf16x8*)(q + c);
        }
    }
    __syncthreads();

    floatx4 acc[2][2];
#pragma unroll
    for (int mt = 0; mt < 2; mt++)
#pragma unroll
        for (int nt = 0; nt < 2; nt++)
            acc[mt][nt] = (floatx4){0.f, 0.f, 0.f, 0.f};

#pragma unroll
    for (int k0 = 0; k0 < 128; k0 += 32) {
        bf16x8 af[2], bf[2];
#pragma unroll
        for (int mt = 0; mt < 2; mt++)
            af[mt] = *(const bf16x8*)&Ps[(wm * 32 + mt * 16 + ln) * 136 + k0 + q8];
#pragma unroll
        for (int nt = 0; nt < 2; nt++)
            bf[nt] = *(const bf16x8*)&Qs[(wn * 32 + nt * 16 + ln) * 136 + k0 + q8];
#pragma unroll
        for (int mt = 0; mt < 2; mt++)
#pragma unroll
            for (int nt = 0; nt < 2; nt++)
                acc[mt][nt] = __builtin_amdgcn_mfma_f32_16x16x32_bf16(
                    af[mt], bf[nt], acc[mt][nt], 0, 0, 0);
    }

#pragma unroll
    for (int mt = 0; mt < 2; mt++)
#pragma unroll
        for (int nt = 0; nt < 2; nt++)
#pragma unroll
            for (int r = 0; r < 4; r++) {
                int row = i0 + wm * 32 + mt * 16 + quad * 4 + r;
                int col = j0 + wn * 32 + nt * 16 + ln;
                out[(size_t)row * 1024 + col] = acc[mt][nt][r];
            }
}

extern "C" void kernel_launch(void* const* d_in, const int* in_sizes, int n_in,
                              void* d_out, int out_size, void* d_ws, size_t ws_size,
                              hipStream_t stream) {
    const float* a     = (const float*)d_in[0];
    const float* b     = (const float*)d_in[1];
    const float* feats = (const float*)d_in[2];
    float* out = (float*)d_out;

    float*   part = (float*)d_ws;                                      // 8 MB fp32 partials
    __bf16*  fkb  = (__bf16*)((char*)d_ws + (size_t)NPART * FKN * 4);  // 512 KB bf16

    gemm1_red<<<dim3(64, NPART), 256, 0, stream>>>(a, b, feats, part, fkb);
    gemm2<<<dim3(16, 16), 256, 0, stream>>>(fkb, out);
}

// Round 7
// 111.764 us; speedup vs baseline: 1.3139x; 1.3139x over previous
//
#include <hip/hip_runtime.h>

// out[1024][1024] = relu(a @ feats^T) @ relu(b @ feats^T)^T
//   a,b: [1024][2048] fp32, feats: [128][2048] fp32, out fp32.
// Pipeline (2 dispatches, NO cross-workgroup communication):
//   gemm1_block: 128 blocks x 512 thr (8 waves). Block owns a 16-row stripe
//                of [a;b] and the FULL K=2048. Waves = 2 feat-halves x 4
//                K-quarters; each wave accumulates K=512 in regs (16 iters
//                of 32); LDS tree-reduce over the 4 K-quarters (syncthreads
//                only); relu+cvt -> bf16 fk[2048][128] written directly.
//   gemm2      : 64x64 out tiles via MFMA on relu'd bf16 fk (R4-verbatim).
// Measured lessons: grid.sync (R1: dual L2 flush+spin), per-elem atomics
// (R2: +30us), consumer-fused reduce (R5: 16x read amp), producer fence+ctr
// (R6: __threadfence = per-block L2 writeback, +50us) ALL lose to a kernel
// boundary. In-block LDS reduce is the only fusion with no global hazard.
// ~44 us ws poison-fill is a fixed term in the timed window.

typedef __attribute__((ext_vector_type(8))) __bf16 bf16x8;
typedef __attribute__((ext_vector_type(4))) __bf16 bf16x4;
typedef __attribute__((ext_vector_type(4))) float floatx4;

#define KD   2048   // inner K of gemm1
#define NF   128    // feature count = K of gemm2
#define NA   1024   // rows of a (= rows of b = out dim)

static __device__ inline bf16x8 cvt8(float4 u, float4 v) {
    bf16x8 s;
    s[0] = (__bf16)u.x; s[1] = (__bf16)u.y; s[2] = (__bf16)u.z; s[3] = (__bf16)u.w;
    s[4] = (__bf16)v.x; s[5] = (__bf16)v.y; s[6] = (__bf16)v.z; s[7] = (__bf16)v.w;
    return s;
}

static __device__ inline bf16x4 cvt4(float4 u) {
    bf16x4 s;
    s[0] = (__bf16)u.x; s[1] = (__bf16)u.y; s[2] = (__bf16)u.z; s[3] = (__bf16)u.w;
    return s;
}

// ---- gemm1_block: fk[m0:m0+16][:] = relu( X[m0:m0+16, :] . feats^T ), bf16
// 8 waves: wf = w&1 (feat-half, 64 cols), wk = w>>1 (K-quarter, 512 each).
// Per iteration the block stages X[16][128] + F[128][128] (one 128-K chunk);
// wave (wf,wk) consumes K-subcols [wk*32, wk*32+32).
__global__ __launch_bounds__(512) void gemm1_block(const float* __restrict__ A,
                                                   const float* __restrict__ B,
                                                   const float* __restrict__ F,
                                                   __bf16* __restrict__ fkb) {
    __shared__ __attribute__((aligned(16))) __bf16 smem[(16 + 128) * 136];
    __bf16* Xs = smem;               // 16 rows x stride 136
    __bf16* Fs = smem + 16 * 136;    // 128 rows x stride 136

    const int t    = threadIdx.x;
    const int m0   = blockIdx.x * 16;
    const float* src = (m0 < NA) ? (A + (size_t)m0 * KD)
                                 : (B + (size_t)(m0 - NA) * KD);

    const int lane = t & 63;
    const int w    = t >> 6;
    const int wf   = w & 1;    // feat-half: cols [wf*64, wf*64+64)
    const int wk   = w >> 1;   // K-quarter: subcols [wk*32, wk*32+32) per chunk
    const int ln   = lane & 15;
    const int quad = lane >> 4;
    const int q8   = quad * 8;
    const int kb   = wk * 32;

    floatx4 acc[4];
#pragma unroll
    for (int nt = 0; nt < 4; nt++) acc[nt] = (floatx4){0.f, 0.f, 0.f, 0.f};

    const int xrow = t >> 5, xcol = (t & 31) * 4;   // 16 rows x 128 cols, 1 float4/thr
    const int frow = t >> 2, fcol = (t & 3) * 32;   // 128 rows x 128 cols, 8 float4/thr
    const float* xp = src + (size_t)xrow * KD + xcol;
    const float* fp = F   + (size_t)frow * KD + fcol;

    // register prefetch of chunk 0
    float4 xu = *(const float4*)(xp);
    float4 fa[8];
#pragma unroll
    for (int i = 0; i < 8; i++) fa[i] = *(const float4*)(fp + 4 * i);

    for (int kk = 0; kk < 16; kk++) {   // 16 chunks of 128 K
        *(bf16x4*)&Xs[xrow * 136 + xcol] = cvt4(xu);
#pragma unroll
        for (int i = 0; i < 4; i++)
            *(bf16x8*)&Fs[frow * 136 + fcol + 8 * i] = cvt8(fa[2 * i], fa[2 * i + 1]);
        __syncthreads();

        if (kk + 1 < 16) {   // prefetch next chunk while MFMAs run
            const int g = (kk + 1) * 128;
            xu = *(const float4*)(xp + g);
#pragma unroll
            for (int i = 0; i < 8; i++) fa[i] = *(const float4*)(fp + g + 4 * i);
        }

        bf16x8 af = *(const bf16x8*)&Xs[ln * 136 + kb + q8];
#pragma unroll
        for (int nt = 0; nt < 4; nt++) {
            bf16x8 bf = *(const bf16x8*)&Fs[(wf * 64 + nt * 16 + ln) * 136 + kb + q8];
            acc[nt] = __builtin_amdgcn_mfma_f32_16x16x32_bf16(af, bf, acc[nt], 0, 0, 0);
        }
        __syncthreads();
    }

    // in-block reduce over the 4 K-quarters via LDS (alias staging buffer)
    float* red = (float*)smem;            // 3 regions of [16][132] fp32
    const int RSTR = 16 * 132;
    if (wk > 0) {
        float* rg = red + (size_t)(wk - 1) * RSTR;
#pragma unroll
        for (int nt = 0; nt < 4; nt++)
#pragma unroll
            for (int r = 0; r < 4; r++)
                rg[(quad * 4 + r) * 132 + wf * 64 + nt * 16 + ln] = acc[nt][r];
    }
    __syncthreads();
    if (wk == 0) {
#pragma unroll
        for (int nt = 0; nt < 4; nt++)
#pragma unroll
            for (int r = 0; r < 4; r++) {
                const int ro = (quad * 4 + r) * 132 + wf * 64 + nt * 16 + ln;
                float v = acc[nt][r] + red[ro] + red[RSTR + ro] + red[2 * RSTR + ro];
                fkb[(size_t)(m0 + quad * 4 + r) * NF + wf * 64 + nt * 16 + ln] =
                    (__bf16)fmaxf(v, 0.f);
            }
    }
}

// ---- gemm2: out[i][j] = sum_f fkb[i][f] * fkb[1024+j][f] (already relu'd) ----
// grid (16,16): 64x64 out tiles; block = 4 waves in 2x2. (R4-verbatim)
__global__ __launch_bounds__(256) void gemm2(const __bf16* __restrict__ fkb,
                                             float* __restrict__ out) {
    __shared__ __bf16 Ps[64 * 136];
    __shared__ __bf16 Qs[64 * 136];

    const int t    = threadIdx.x;
    const int i0   = blockIdx.y * 64;
    const int j0   = blockIdx.x * 64;
    const int lane = t & 63;
    const int w    = t >> 6;
    const int wm   = w & 1;
    const int wn   = w >> 1;
    const int ln   = lane & 15;
    const int quad = lane >> 4;
    const int q8   = quad * 8;

    const int prow = t >> 2, pcol = (t & 3) * 32;
    {
        const __bf16* p = fkb + (size_t)(i0 + prow) * NF + pcol;
        const __bf16* q = fkb + (size_t)(NA + j0 + prow) * NF + pcol;
#pragma unroll
        for (int c = 0; c < 32; c += 8) {
            *(bf16x8*)&Ps[prow * 136 + pcol + c] = *(const bf16x8*)(p + c);
            *(bf16x8*)&Qs[prow * 136 + pcol + c] = *(const bf16x8*)(q + c);
        }
    }
    __syncthreads();

    floatx4 acc[2][2];
#pragma unroll
    for (int mt = 0; mt < 2; mt++)
#pragma unroll
        for (int nt = 0; nt < 2; nt++)
            acc[mt][nt] = (floatx4){0.f, 0.f, 0.f, 0.f};

#pragma unroll
    for (int k0 = 0; k0 < 128; k0 += 32) {
        bf16x8 af[2], bf[2];
#pragma unroll
        for (int mt = 0; mt < 2; mt++)
            af[mt] = *(const bf16x8*)&Ps[(wm * 32 + mt * 16 + ln) * 136 + k0 + q8];
#pragma unroll
        for (int nt = 0; nt < 2; nt++)
            bf[nt] = *(const bf16x8*)&Qs[(wn * 32 + nt * 16 + ln) * 136 + k0 + q8];
#pragma unroll
        for (int mt = 0; mt < 2; mt++)
#pragma unroll
            for (int nt = 0; nt < 2; nt++)
                acc[mt][nt] = __builtin_amdgcn_mfma_f32_16x16x32_bf16(
                    af[mt], bf[nt], acc[mt][nt], 0, 0, 0);
    }

#pragma unroll
    for (int mt = 0; mt < 2; mt++)
#pragma unroll
        for (int nt = 0; nt < 2; nt++)
#pragma unroll
            for (int r = 0; r < 4; r++) {
                int row = i0 + wm * 32 + mt * 16 + quad * 4 + r;
                int col = j0 + wn * 32 + nt * 16 + ln;
                out[(size_t)row * 1024 + col] = acc[mt][nt][r];
            }
}

extern "C" void kernel_launch(void* const* d_in, const int* in_sizes, int n_in,
                              void* d_out, int out_size, void* d_ws, size_t ws_size,
                              hipStream_t stream) {
    const float* a     = (const float*)d_in[0];
    const float* b     = (const float*)d_in[1];
    const float* feats = (const float*)d_in[2];
    float* out = (float*)d_out;

    __bf16* fkb = (__bf16*)d_ws;   // 2048 x 128 bf16, relu'd (512 KB)

    gemm1_block<<<128, 512, 0, stream>>>(a, b, feats, fkb);
    gemm2<<<dim3(16, 16), 256, 0, stream>>>(fkb, out);
}

// Round 8
// 87.538 us; speedup vs baseline: 1.6775x; 1.2767x over previous
//
#include <hip/hip_runtime.h>

// out[1024][1024] = relu(a @ feats^T) @ relu(b @ feats^T)^T
//   a,b: [1024][2048] fp32, feats: [128][2048] fp32, out fp32.
// Pipeline (2 dispatches, NO cross-workgroup communication):
//   gemm1_coal: 128 blocks x 512 thr (8 waves). Block owns a 16-row stripe of
//               [a;b] and the FULL K=2048. Waves = 2 feat-halves x 4
//               K-quarters; 16 chunks of 128 K staged to LDS with FULLY
//               COALESCED loads (R7's strided F-staging caused 4x L1
//               line-request inflation -> 53 us); in-block LDS tree-reduce
//               over K-quarters; relu+cvt -> bf16 fk[2048][128].
//   gemm2     : 64x64 out tiles via MFMA on relu'd bf16 fk (R4-verbatim).
// Measured lessons: grid.sync (R1), per-elem atomics (R2), consumer-fused
// reduce (R5: 16x read amp), producer fence+ctr (R6: per-block L2 writeback)
// all lose to a kernel boundary. gemm1-style kernels are L1-request bound:
// every wave-instr must touch contiguous 1024 B (R3/R7: 64 lines/instr = 53
// us regardless of iteration count). ~44 us ws poison-fill is a fixed term.

typedef __attribute__((ext_vector_type(8))) __bf16 bf16x8;
typedef __attribute__((ext_vector_type(4))) __bf16 bf16x4;
typedef __attribute__((ext_vector_type(4))) float floatx4;

#define KD   2048   // inner K of gemm1
#define NF   128    // feature count = K of gemm2
#define NA   1024   // rows of a (= rows of b = out dim)

static __device__ inline bf16x4 cvt4(float4 u) {
    bf16x4 s;
    s[0] = (__bf16)u.x; s[1] = (__bf16)u.y; s[2] = (__bf16)u.z; s[3] = (__bf16)u.w;
    return s;
}

static __device__ inline bf16x8 cvt8(float4 u, float4 v) {
    bf16x8 s;
    s[0] = (__bf16)u.x; s[1] = (__bf16)u.y; s[2] = (__bf16)u.z; s[3] = (__bf16)u.w;
    s[4] = (__bf16)v.x; s[5] = (__bf16)v.y; s[6] = (__bf16)v.z; s[7] = (__bf16)v.w;
    return s;
}

// ---- gemm1_coal: fk[m0:m0+16][:] = relu( X[m0:m0+16, :] . feats^T ), bf16
// 8 waves: wf = w&1 (feat-half, 64 cols), wk = w>>1 (K-quarter of each chunk).
// Per chunk the block stages X[16][128] + F[128][128]; all staging loads are
// coalesced: consecutive lanes read consecutive float4s of the same row.
__global__ __launch_bounds__(512) void gemm1_coal(const float* __restrict__ A,
                                                  const float* __restrict__ B,
                                                  const float* __restrict__ F,
                                                  __bf16* __restrict__ fkb) {
    __shared__ __attribute__((aligned(16))) __bf16 smem[(16 + 128) * 136];
    __bf16* Xs = smem;               // 16 rows x stride 136
    __bf16* Fs = smem + 16 * 136;    // 128 rows x stride 136

    const int t    = threadIdx.x;
    const int m0   = blockIdx.x * 16;
    const float* src = (m0 < NA) ? (A + (size_t)m0 * KD)
                                 : (B + (size_t)(m0 - NA) * KD);

    const int lane = t & 63;
    const int w    = t >> 6;
    const int wf   = w & 1;    // feat-half: cols [wf*64, wf*64+64)
    const int wk   = w >> 1;   // K-quarter: subcols [wk*32, wk*32+32) per chunk
    const int ln   = lane & 15;
    const int quad = lane >> 4;
    const int q8   = quad * 8;
    const int kb   = wk * 32;

    floatx4 acc[4];
#pragma unroll
    for (int nt = 0; nt < 4; nt++) acc[nt] = (floatx4){0.f, 0.f, 0.f, 0.f};

    // coalesced staging coordinates: row_base advances by 16 per i-step for F
    const int srow = t >> 5;          // 0..15
    const int scol = (t & 31) * 4;    // float col 0..124, 16B-aligned
    const float* xp = src + (size_t)srow * KD + scol;   // X: 1 float4/thr
    const float* fp = F   + (size_t)srow * KD + scol;   // F: rows srow+16*i

    // register prefetch of chunk 0
    float4 xu = *(const float4*)(xp);
    float4 fa[8];
#pragma unroll
    for (int i = 0; i < 8; i++)
        fa[i] = *(const float4*)(fp + (size_t)i * 16 * KD);

    for (int kk = 0; kk < 16; kk++) {   // 16 chunks of 128 K
        *(bf16x4*)&Xs[srow * 136 + scol] = cvt4(xu);
#pragma unroll
        for (int i = 0; i < 8; i++)
            *(bf16x4*)&Fs[(i * 16 + srow) * 136 + scol] = cvt4(fa[i]);
        __syncthreads();

        if (kk + 1 < 16) {   // prefetch next chunk while MFMAs run
            const int g = (kk + 1) * 128;
            xu = *(const float4*)(xp + g);
#pragma unroll
            for (int i = 0; i < 8; i++)
                fa[i] = *(const float4*)(fp + (size_t)i * 16 * KD + g);
        }

        bf16x8 af = *(const bf16x8*)&Xs[ln * 136 + kb + q8];
#pragma unroll
        for (int nt = 0; nt < 4; nt++) {
            bf16x8 bf = *(const bf16x8*)&Fs[(wf * 64 + nt * 16 + ln) * 136 + kb + q8];
            acc[nt] = __builtin_amdgcn_mfma_f32_16x16x32_bf16(af, bf, acc[nt], 0, 0, 0);
        }
        __syncthreads();
    }

    // in-block reduce over the 4 K-quarters via LDS (alias staging buffer)
    float* red = (float*)smem;            // 3 regions of [16][132] fp32
    const int RSTR = 16 * 132;
    if (wk > 0) {
        float* rg = red + (size_t)(wk - 1) * RSTR;
#pragma unroll
        for (int nt = 0; nt < 4; nt++)
#pragma unroll
            for (int r = 0; r < 4; r++)
                rg[(quad * 4 + r) * 132 + wf * 64 + nt * 16 + ln] = acc[nt][r];
    }
    __syncthreads();
    if (wk == 0) {
#pragma unroll
        for (int nt = 0; nt < 4; nt++)
#pragma unroll
            for (int r = 0; r < 4; r++) {
                const int ro = (quad * 4 + r) * 132 + wf * 64 + nt * 16 + ln;
                float v = acc[nt][r] + red[ro] + red[RSTR + ro] + red[2 * RSTR + ro];
                fkb[(size_t)(m0 + quad * 4 + r) * NF + wf * 64 + nt * 16 + ln] =
                    (__bf16)fmaxf(v, 0.f);
            }
    }
}

// ---- gemm2: out[i][j] = sum_f fkb[i][f] * fkb[1024+j][f] (already relu'd) ----
// grid (16,16): 64x64 out tiles; block = 4 waves in 2x2. (R4-verbatim)
__global__ __launch_bounds__(256) void gemm2(const __bf16* __restrict__ fkb,
                                             float* __restrict__ out) {
    __shared__ __bf16 Ps[64 * 136];
    __shared__ __bf16 Qs[64 * 136];

    const int t    = threadIdx.x;
    const int i0   = blockIdx.y * 64;
    const int j0   = blockIdx.x * 64;
    const int lane = t & 63;
    const int w    = t >> 6;
    const int wm   = w & 1;
    const int wn   = w >> 1;
    const int ln   = lane & 15;
    const int quad = lane >> 4;
    const int q8   = quad * 8;

    const int prow = t >> 2, pcol = (t & 3) * 32;
    {
        const __bf16* p = fkb + (size_t)(i0 + prow) * NF + pcol;
        const __bf16* q = fkb + (size_t)(NA + j0 + prow) * NF + pcol;
#pragma unroll
        for (int c = 0; c < 32; c += 8) {
            *(bf16x8*)&Ps[prow * 136 + pcol + c] = *(const bf16x8*)(p + c);
            *(bf16x8*)&Qs[prow * 136 + pcol + c] = *(const bf16x8*)(q + c);
        }
    }
    __syncthreads();

    floatx4 acc[2][2];
#pragma unroll
    for (int mt = 0; mt < 2; mt++)
#pragma unroll
        for (int nt = 0; nt < 2; nt++)
            acc[mt][nt] = (floatx4){0.f, 0.f, 0.f, 0.f};

#pragma unroll
    for (int k0 = 0; k0 < 128; k0 += 32) {
        bf16x8 af[2], bf[2];
#pragma unroll
        for (int mt = 0; mt < 2; mt++)
            af[mt] = *(const bf16x8*)&Ps[(wm * 32 + mt * 16 + ln) * 136 + k0 + q8];
#pragma unroll
        for (int nt = 0; nt < 2; nt++)
            bf[nt] = *(const bf16x8*)&Qs[(wn * 32 + nt * 16 + ln) * 136 + k0 + q8];
#pragma unroll
        for (int mt = 0; mt < 2; mt++)
#pragma unroll
            for (int nt = 0; nt < 2; nt++)
                acc[mt][nt] = __builtin_amdgcn_mfma_f32_16x16x32_bf16(
                    af[mt], bf[nt], acc[mt][nt], 0, 0, 0);
    }

#pragma unroll
    for (int mt = 0; mt < 2; mt++)
#pragma unroll
        for (int nt = 0; nt < 2; nt++)
#pragma unroll
            for (int r = 0; r < 4; r++) {
                int row = i0 + wm * 32 + mt * 16 + quad * 4 + r;
                int col = j0 + wn * 32 + nt * 16 + ln;
                out[(size_t)row * 1024 + col] = acc[mt][nt][r];
            }
}

extern "C" void kernel_launch(void* const* d_in, const int* in_sizes, int n_in,
                              void* d_out, int out_size, void* d_ws, size_t ws_size,
                              hipStream_t stream) {
    const float* a     = (const float*)d_in[0];
    const float* b     = (const float*)d_in[1];
    const float* feats = (const float*)d_in[2];
    float* out = (float*)d_out;

    __bf16* fkb = (__bf16*)d_ws;   // 2048 x 128 bf16, relu'd (512 KB)

    gemm1_coal<<<128, 512, 0, stream>>>(a, b, feats, fkb);
    gemm2<<<dim3(16, 16), 256, 0, stream>>>(fkb, out);
}

// Round 9
// 78.510 us; speedup vs baseline: 1.8704x; 1.1150x over previous
//
#include <hip/hip_runtime.h>

// out[1024][1024] = relu(a @ feats^T) @ relu(b @ feats^T)^T
//   a,b: [1024][2048] fp32, feats: [128][2048] fp32, out fp32.
// Pipeline (3 dispatches — R4's proven best, with fully-coalesced gemm1
// staging, the one lesson from R7/R8 that was never applied to R4):
//   gemm1_part8: grid (64,8) = 32-row M-stripes x 8 K-splits (K=256, 4 iters
//                of 64) -> fp32 partials part[8][2048][128] (8 MB)
//   reduce_relu: sum 8 partials, relu, cvt -> bf16 fk[2048][128] (512 KB)
//   gemm2      : 64x64 out tiles via MFMA on relu'd bf16 fk
// Measured lessons: grid.sync (R1), per-elem atomics (R2), consumer-fused
// reduce (R5: 16x read amp), producer fence+ctr (R6: per-block L2 writeback),
// full-K-per-block (R3/R7/R8: half the CUs + long serial chain) all lose to
// this split-K + plain-dispatch shape. Staging must be fully coalesced:
// every wave-instr reads 16 consecutive rows x 256 contiguous B (R8 proof:
// strided F staging = 4x L1 line inflation = +24 us). ~44 us ws poison-fill
// is a fixed term in the timed window.

typedef __attribute__((ext_vector_type(8))) __bf16 bf16x8;
typedef __attribute__((ext_vector_type(4))) __bf16 bf16x4;
typedef __attribute__((ext_vector_type(4))) float floatx4;

#define KD     2048   // inner K of gemm1
#define NF     128    // feature count = K of gemm2
#define NA     1024   // rows of a (= rows of b = out dim)
#define NPART  8      // K-splits (K=256 each)
#define KSL    256    // K per split
#define FKN    (2048 * 128)

static __device__ inline bf16x4 cvt4(float4 u) {
    bf16x4 s;
    s[0] = (__bf16)u.x; s[1] = (__bf16)u.y; s[2] = (__bf16)u.z; s[3] = (__bf16)u.w;
    return s;
}

// ---- gemm1_part8: part[s][m0:m0+32][0:128] = X[m0:m0+32, s*256:(s+1)*256] . feats^T
// block = 4 waves; wave w covers feat-cols [w*32, w*32+32). 4 K-iters of 64.
// Staging fully coalesced: job j -> row j>>4, float-col (j&15)*4; each
// wave-instruction touches 16 consecutive rows x 256 contiguous bytes.
__global__ __launch_bounds__(256) void gemm1_part8(const float* __restrict__ A,
                                                   const float* __restrict__ B,
                                                   const float* __restrict__ F,
                                                   float* __restrict__ part) {
    __shared__ __bf16 Xs[32 * 72];    // 32 rows x 64 K-cols, stride 72
    __shared__ __bf16 Fs[128 * 72];   // 128 feat-rows x 64 K-cols

    const int t    = threadIdx.x;
    const int m0   = blockIdx.x * 32;
    const int s    = blockIdx.y;
    const int k0   = s * KSL;
    const float* src = (m0 < NA) ? (A + (size_t)m0 * KD)
                                 : (B + (size_t)(m0 - NA) * KD);

    const int lane = t & 63;
    const int w    = t >> 6;
    const int ln   = lane & 15;
    const int quad = lane >> 4;
    const int q8   = quad * 8;

    floatx4 acc[2][2];
#pragma unroll
    for (int mt = 0; mt < 2; mt++)
#pragma unroll
        for (int nt = 0; nt < 2; nt++)
            acc[mt][nt] = (floatx4){0.f, 0.f, 0.f, 0.f};

    // coalesced staging coordinates (shared by X and F)
    const int srow = t >> 4;          // 0..15
    const int scol = (t & 15) * 4;    // float col 0..60 within the 64-col chunk
    const float* xp0 = src + (size_t)srow * KD        + (k0 + scol);  // X rows srow, srow+16
    const float* xp1 = src + (size_t)(srow + 16) * KD + (k0 + scol);
    const float* fp  = F   + (size_t)srow * KD        + (k0 + scol);  // F rows srow + 16*i

    // register prefetch of kk=0
    float4 x0 = *(const float4*)(xp0);
    float4 x1 = *(const float4*)(xp1);
    float4 fa[8];
#pragma unroll
    for (int i = 0; i < 8; i++)
        fa[i] = *(const float4*)(fp + (size_t)i * 16 * KD);

#pragma unroll
    for (int kk = 0; kk < KSL; kk += 64) {
        *(bf16x4*)&Xs[srow * 72 + scol]        = cvt4(x0);
        *(bf16x4*)&Xs[(srow + 16) * 72 + scol] = cvt4(x1);
#pragma unroll
        for (int i = 0; i < 8; i++)
            *(bf16x4*)&Fs[(i * 16 + srow) * 72 + scol] = cvt4(fa[i]);
        __syncthreads();

        if (kk + 64 < KSL) {   // prefetch next K-chunk while MFMAs run
            x0 = *(const float4*)(xp0 + kk + 64);
            x1 = *(const float4*)(xp1 + kk + 64);
#pragma unroll
            for (int i = 0; i < 8; i++)
                fa[i] = *(const float4*)(fp + (size_t)i * 16 * KD + kk + 64);
        }

#pragma unroll
        for (int sub = 0; sub < 64; sub += 32) {
            bf16x8 bfrag[2];
#pragma unroll
            for (int nt = 0; nt < 2; nt++)
                bfrag[nt] = *(const bf16x8*)&Fs[(w * 32 + nt * 16 + ln) * 72 + sub + q8];
#pragma unroll
            for (int mt = 0; mt < 2; mt++) {
                bf16x8 af = *(const bf16x8*)&Xs[(mt * 16 + ln) * 72 + sub + q8];
#pragma unroll
                for (int nt = 0; nt < 2; nt++)
                    acc[mt][nt] = __builtin_amdgcn_mfma_f32_16x16x32_bf16(
                        af, bfrag[nt], acc[mt][nt], 0, 0, 0);
            }
        }
        __syncthreads();
    }

    float* pdst = part + (size_t)s * FKN;
#pragma unroll
    for (int mt = 0; mt < 2; mt++)
#pragma unroll
        for (int nt = 0; nt < 2; nt++)
#pragma unroll
            for (int r = 0; r < 4; r++) {
                int row = m0 + mt * 16 + quad * 4 + r;
                int col = w * 32 + nt * 16 + ln;
                pdst[(size_t)row * NF + col] = acc[mt][nt][r];
            }
}

// ---- reduce_relu: fkb[i] = bf16(relu(sum_s part[s][i])), vectorized x4 ----
__global__ __launch_bounds__(256) void reduce_relu(const float* __restrict__ part,
                                                   __bf16* __restrict__ fkb) {
    int idx = blockIdx.x * 256 + threadIdx.x;   // 65536 threads, 4 floats each
    size_t base = (size_t)idx * 4;
    float4 sum = make_float4(0.f, 0.f, 0.f, 0.f);
#pragma unroll
    for (int s = 0; s < NPART; s++) {
        float4 u = *(const float4*)(part + (size_t)s * FKN + base);
        sum.x += u.x; sum.y += u.y; sum.z += u.z; sum.w += u.w;
    }
    bf16x4 o;
    o[0] = (__bf16)fmaxf(sum.x, 0.f);
    o[1] = (__bf16)fmaxf(sum.y, 0.f);
    o[2] = (__bf16)fmaxf(sum.z, 0.f);
    o[3] = (__bf16)fmaxf(sum.w, 0.f);
    *(bf16x4*)(fkb + base) = o;
}

// ---- gemm2: out[i][j] = sum_f fkb[i][f] * fkb[1024+j][f] (already relu'd) ----
// grid (16,16): 64x64 out tiles; block = 4 waves in 2x2. (R4-verbatim)
__global__ __launch_bounds__(256) void gemm2(const __bf16* __restrict__ fkb,
                                             float* __restrict__ out) {
    __shared__ __bf16 Ps[64 * 136];
    __shared__ __bf16 Qs[64 * 136];

    const int t    = threadIdx.x;
    const int i0   = blockIdx.y * 64;
    const int j0   = blockIdx.x * 64;
    const int lane = t & 63;
    const int w    = t >> 6;
    const int wm   = w & 1;
    const int wn   = w >> 1;
    const int ln   = lane & 15;
    const int quad = lane >> 4;
    const int q8   = quad * 8;

    const int prow = t >> 2, pcol = (t & 3) * 32;
    {
        const __bf16* p = fkb + (size_t)(i0 + prow) * NF + pcol;
        const __bf16* q = fkb + (size_t)(NA + j0 + prow) * NF + pcol;
#pragma unroll
        for (int c = 0; c < 32; c += 8) {
            *(bf16x8*)&Ps[prow * 136 + pcol + c] = *(const bf16x8*)(p + c);
            *(bf16x8*)&Qs[prow * 136 + pcol + c] = *(const bf16x8*)(q + c);
        }
    }
    __syncthreads();

    floatx4 acc[2][2];
#pragma unroll
    for (int mt = 0; mt < 2; mt++)
#pragma unroll
        for (int nt = 0; nt < 2; nt++)
            acc[mt][nt] = (floatx4){0.f, 0.f, 0.f, 0.f};

#pragma unroll
    for (int k0 = 0; k0 < 128; k0 += 32) {
        bf16x8 af[2], bf[2];
#pragma unroll
        for (int mt = 0; mt < 2; mt++)
            af[mt] = *(const bf16x8*)&Ps[(wm * 32 + mt * 16 + ln) * 136 + k0 + q8];
#pragma unroll
        for (int nt = 0; nt < 2; nt++)
            bf[nt] = *(const bf16x8*)&Qs[(wn * 32 + nt * 16 + ln) * 136 + k0 + q8];
#pragma unroll
        for (int mt = 0; mt < 2; mt++)
#pragma unroll
            for (int nt = 0; nt < 2; nt++)
                acc[mt][nt] = __builtin_amdgcn_mfma_f32_16x16x32_bf16(
                    af[mt], bf[nt], acc[mt][nt], 0, 0, 0);
    }

#pragma unroll
    for (int mt = 0; mt < 2; mt++)
#pragma unroll
        for (int nt = 0; nt < 2; nt++)
#pragma unroll
            for (int r = 0; r < 4; r++) {
                int row = i0 + wm * 32 + mt * 16 + quad * 4 + r;
                int col = j0 + wn * 32 + nt * 16 + ln;
                out[(size_t)row * 1024 + col] = acc[mt][nt][r];
            }
}

extern "C" void kernel_launch(void* const* d_in, const int* in_sizes, int n_in,
                              void* d_out, int out_size, void* d_ws, size_t ws_size,
                              hipStream_t stream) {
    const float* a     = (const float*)d_in[0];
    const float* b     = (const float*)d_in[1];
    const float* feats = (const float*)d_in[2];
    float* out = (float*)d_out;

    float*   part = (float*)d_ws;                                      // 8 MB fp32 partials
    __bf16*  fkb  = (__bf16*)((char*)d_ws + (size_t)NPART * FKN * 4);  // 512 KB bf16

    gemm1_part8<<<dim3(64, NPART), 256, 0, stream>>>(a, b, feats, part);
    reduce_relu<<<256, 256, 0, stream>>>(part, fkb);
    gemm2<<<dim3(16, 16), 256, 0, stream>>>(fkb, out);
}